// Round 7
// baseline (209.862 us; speedup 1.0000x reference)
//
#include <hip/hip_runtime.h>

#define MM 128
#define NN 128
#define KK 128
#define NB 4
#define ITERS 8
#define WIN 10
#define WSTRIDE 12
#define PLANE (WIN * WSTRIDE)   // wp stride: 10 wk-rows of 12
#define BUFSZ (WIN * PLANE)     // 1200 floats per window buffer
#define MNK (MM * NN * KK)

__device__ __forceinline__ float wave_sum(float v) {
  v += __shfl_xor(v, 32, 64);
  v += __shfl_xor(v, 16, 64);
  v += __shfl_xor(v, 8, 64);
  v += __shfl_xor(v, 4, 64);
  v += __shfl_xor(v, 2, 64);
  v += __shfl_xor(v, 1, 64);
  return v;
}

// Force a block-uniform value into an SGPR (frees VGPR pressure).
__device__ __forceinline__ float bcast_first(float v) {
  return __uint_as_float(__builtin_amdgcn_readfirstlane(__float_as_uint(v)));
}

// One workgroup (256 threads = 4 waves) per 8^3 spatial block. Thread t owns a
// (1,1,2) micro-tile: p = t>>5, q = (t>>2)&7, r0 = 2*(t&3); 2x27 conv weights
// in registers (batch-invariant). All 4 batches in flight.
//
// KEY SIZING INSIGHT (R1/R2/R5/R6 spill pattern): the AMDGPU backend derives
// its occupancy target from LDS usage and SPILLS VGPRs to reach it:
//   19.5KB LDS -> 8 WGs fit -> target 8 waves/EU -> 64-VGPR budget -> spill.
// Attributes (waves_per_eu, launch_bounds min) did not override it. So we
// size LDS to 38.9KB (4 WGs/CU) -> target 4 waves/EU -> 128-VGPR budget,
// which fits the ~100 this kernel actually needs. The "extra" LDS is spent
// productively: PING-PONG window buffers -> the WAR barrier disappears ->
// ONE barrier per inner iteration (8 phases total, was 16).
//
// red[] banks alternate per iteration parity: a writer of bank(it+2) has
// passed barrier(it+1), and every reader of bank(it) read it before reaching
// barrier(it+1) -> single-barrier reduce is race-free.
// LDS window TRANSPOSED: addr = wp*120 + wk*12 + wq -> conv b32 reads hit
// every bank exactly 2x per wave (free; R4 cut conflicts 63x).
__global__ __launch_bounds__(256, 4) void gridnet_kernel(
    const float* __restrict__ weight, const float* __restrict__ bias,
    const float* __restrict__ rscale, const float* __restrict__ x,
    float* __restrict__ out) {
  __shared__ float Wl[NB][2][BUFSZ];   // 38400 B
  __shared__ float red[128];           // [0,64): staging; [64,96)/[96,128): iter banks

  const int t = threadIdx.x;
  const int r0 = (t & 3) * 2, q = (t >> 2) & 7, p = t >> 5;
  const int wv = t >> 6;

  // XCD swizzle: adjacent-bk spatial blocks (sharing 64B weight/x lines) land
  // on the same XCD -> second read hits that XCD's L2. (FETCH 575->139MB.)
  const int d = blockIdx.x;
  const int sp = (d & 7) * 512 + (d >> 3);
  const int bm = sp >> 8, bn = (sp >> 4) & 15, bk = sp & 15;

  const int gm0 = bm * 8, gn0 = bn * 8, gk0 = bk * 8;
  const int g = ((gm0 + p) * NN + (gn0 + q)) * KK + (gk0 + r0);

  // per-thread weights: w0/w1 = the two k-cells, o = i*9 + j*3 + k
  float w0[27], w1[27];
  float S0 = 0.f, S1 = 0.f;
#pragma unroll
  for (int o = 0; o < 27; ++o) {
    float2 wv2 = *(const float2*)(weight + o * MNK + g);
    w0[o] = wv2.x; w1[o] = wv2.y;
    S0 += wv2.x;   S1 += wv2.y;
  }
  const float2 bv = *(const float2*)(bias + g);
  const float2 rv = *(const float2*)(rscale + g);

  // transposed window coords: addr(wp,wk,wq) = wp*PLANE + wk*WSTRIDE + wq
  const int cb = p * PLANE + r0 * WSTRIDE + q;   // (i=0,jj=0,k=0) tap
  const int wb = cb + PLANE + WSTRIDE + 1;       // own cell dr=0; dr=1 at +WSTRIDE

  // ---- stage all 4 batch windows into buf0; halo mirrored into buf1 ----
  float sA[NB] = {0.f, 0.f, 0.f, 0.f}, sAq[NB] = {0.f, 0.f, 0.f, 0.f};
  float sH[NB] = {0.f, 0.f, 0.f, 0.f}, sHq[NB] = {0.f, 0.f, 0.f, 0.f};
  for (int idx = t; idx < 1000; idx += 256) {
    int wp_ = idx / 100;
    int rem = idx - wp_ * 100;
    int wq = rem / 10;
    int wk = rem - wq * 10;
    int gm = gm0 - 1 + wp_, gn = gn0 - 1 + wq, gk = gk0 - 1 + wk;
    const bool inb = (unsigned)gm < 128u && (unsigned)gn < 128u && (unsigned)gk < 128u;
    const bool halo = (wp_ == 0 || wp_ == 9 || wq == 0 || wq == 9 || wk == 0 || wk == 9);
    const int gx = (gm * NN + gn) * KK + gk;        // only used when inb
    const int li = wp_ * PLANE + wk * WSTRIDE + wq; // transposed store
#pragma unroll
    for (int b = 0; b < NB; ++b) {
      float v = 0.f;
      if (inb) v = x[b * MNK + gx];
      Wl[b][0][li] = v;
      sA[b] += v; sAq[b] += v * v;
      if (halo) { Wl[b][1][li] = v; sH[b] += v; sHq[b] += v * v; }
    }
  }
#pragma unroll
  for (int b = 0; b < NB; ++b) {
    sA[b] = wave_sum(sA[b]);  sAq[b] = wave_sum(sAq[b]);
    sH[b] = wave_sum(sH[b]);  sHq[b] = wave_sum(sHq[b]);
  }
  if ((t & 63) == 0) {
#pragma unroll
    for (int b = 0; b < NB; ++b) {
      float4 pk; pk.x = sA[b]; pk.y = sAq[b]; pk.z = sH[b]; pk.w = sHq[b];
      *(float4*)&red[(wv * NB + b) * 4] = pk;
    }
  }
  __syncthreads();

  float invv[NB], imv[NB], hS[NB], hQ[NB];  // block-uniform -> SGPRs
#pragma unroll
  for (int b = 0; b < NB; ++b) {
    float tS = 0.f, tQ = 0.f, hs = 0.f, hq = 0.f;
#pragma unroll
    for (int i = 0; i < 4; ++i) {
      float4 pk = *(const float4*)&red[(i * NB + b) * 4];  // broadcast read
      tS += pk.x; tQ += pk.y; hs += pk.z; hq += pk.w;
    }
    hS[b] = bcast_first(hs); hQ[b] = bcast_first(hq);
    float mu = tS * (1.0f / 1000.0f);
    float var = tQ * (1.0f / 1000.0f) - mu * mu;
    float inv = __builtin_amdgcn_rsqf(var + 1e-5f);
    invv[b] = bcast_first(inv); imv[b] = bcast_first(inv * mu);
  }
  float a[NB][2];
#pragma unroll
  for (int b = 0; b < NB; ++b) {
    a[b][0] = Wl[b][0][wb];
    a[b][1] = Wl[b][0][wb + WSTRIDE];
  }

#pragma unroll 2
  for (int it = 0; it < ITERS; ++it) {
    const int cur = it & 1;
    // ---- 3^3 locally-connected conv + silu, all 4 batches, from buf[cur] ----
    // (normalization folded: z = bias + inv*conv_raw - inv*mu*S)
#pragma unroll
    for (int b = 0; b < NB; ++b) {
      const float* __restrict__ cp = &Wl[b][cur][cb];
      float acc0 = 0.f, acc1 = 0.f;
#pragma unroll
      for (int i = 0; i < 3; ++i) {
#pragma unroll
        for (int jj = 0; jj < 3; ++jj) {
          const float* rp = cp + i * PLANE + jj;
          float u0 = rp[0];
          float u1 = rp[WSTRIDE];
          float u2 = rp[2 * WSTRIDE];
          float u3 = rp[3 * WSTRIDE];
          const int o = i * 9 + jj * 3;
          acc0 += w0[o] * u0 + w0[o + 1] * u1 + w0[o + 2] * u2;
          acc1 += w1[o] * u1 + w1[o + 1] * u2 + w1[o + 2] * u3;
        }
      }
      float z0 = bv.x + invv[b] * acc0 - imv[b] * S0;
      float z1 = bv.y + invv[b] * acc1 - imv[b] * S1;
      float sg0 = __builtin_amdgcn_rcpf(1.0f + __expf(-z0));
      float sg1 = __builtin_amdgcn_rcpf(1.0f + __expf(-z1));
      a[b][0] += rv.x * (z0 * sg0);
      a[b][1] += rv.y * (z1 * sg1);
    }
    if (it == ITERS - 1) break;
    // ---- write new interiors into buf[cur^1] (WAR-safe: buf[cur^1] readers
    // finished before the barrier at the end of the previous iteration) ----
    float ls[NB], lq[NB];
#pragma unroll
    for (int b = 0; b < NB; ++b) {
      Wl[b][cur ^ 1][wb] = a[b][0];
      Wl[b][cur ^ 1][wb + WSTRIDE] = a[b][1];
      ls[b] = wave_sum(a[b][0] + a[b][1]);
      lq[b] = wave_sum(a[b][0] * a[b][0] + a[b][1] * a[b][1]);
    }
    const int bank = 64 + cur * 32;  // alternate banks: single-barrier race-free
    if ((t & 63) == 0) {
#pragma unroll
      for (int b = 0; b < NB; ++b) {
        float2 pk; pk.x = ls[b]; pk.y = lq[b];
        *(float2*)&red[bank + (wv * NB + b) * 2] = pk;
      }
    }
    __syncthreads();  // ONE barrier: interiors visible + partials ready
#pragma unroll
    for (int b = 0; b < NB; ++b) {
      float tS = hS[b], tQ = hQ[b];
#pragma unroll
      for (int i = 0; i < 4; ++i) {
        float2 pk = *(const float2*)&red[bank + (i * NB + b) * 2];  // broadcast
        tS += pk.x; tQ += pk.y;
      }
      float mu = tS * (1.0f / 1000.0f);
      float var = tQ * (1.0f / 1000.0f) - mu * mu;
      float inv = __builtin_amdgcn_rsqf(var + 1e-5f);
      invv[b] = bcast_first(inv); imv[b] = bcast_first(inv * mu);
    }
  }
  // ---- final interiors from registers (r0 even -> float2-aligned) ----
#pragma unroll
  for (int b = 0; b < NB; ++b) {
    float2 ov; ov.x = a[b][0]; ov.y = a[b][1];
    *(float2*)(out + b * MNK + g) = ov;
  }
}

extern "C" void kernel_launch(void* const* d_in, const int* in_sizes, int n_in,
                              void* d_out, int out_size, void* d_ws, size_t ws_size,
                              hipStream_t stream) {
  const float* weight = (const float*)d_in[0];
  const float* bias   = (const float*)d_in[1];
  const float* rscale = (const float*)d_in[2];
  const float* x      = (const float*)d_in[3];
  // d_in[4] = inner_iterations (8), d_in[5] = block_size (8): fixed by harness
  float* out = (float*)d_out;
  gridnet_kernel<<<dim3(16 * 16 * 16), dim3(256), 0, stream>>>(
      weight, bias, rscale, x, out);
}

// Round 8
// 175.684 us; speedup vs baseline: 1.1945x; 1.1945x over previous
//
#include <hip/hip_runtime.h>

#define MM 128
#define NN 128
#define KK 128
#define NB 4
#define ITERS 8
#define WIN 10
#define WSTRIDE 12
#define PLANE (WIN * WSTRIDE)   // wp stride: 10 wk-rows of 12
#define BUFSZ (WIN * PLANE)     // 1200 floats per window buffer
#define MNK (MM * NN * KK)

// Wave-64 sum via DPP adds (no DS-pipe traffic, short dep chain).
// Result valid in LANE 63 only.
__device__ __forceinline__ float wave_sum63(float v) {
  v += __int_as_float(__builtin_amdgcn_update_dpp(
      0, __float_as_int(v), 0x111, 0xF, 0xF, true));  // row_shr:1
  v += __int_as_float(__builtin_amdgcn_update_dpp(
      0, __float_as_int(v), 0x112, 0xF, 0xF, true));  // row_shr:2
  v += __int_as_float(__builtin_amdgcn_update_dpp(
      0, __float_as_int(v), 0x114, 0xF, 0xF, true));  // row_shr:4
  v += __int_as_float(__builtin_amdgcn_update_dpp(
      0, __float_as_int(v), 0x118, 0xF, 0xF, true));  // row_shr:8
  v += __int_as_float(__builtin_amdgcn_update_dpp(
      0, __float_as_int(v), 0x142, 0xF, 0xF, true));  // row_bcast:15
  v += __int_as_float(__builtin_amdgcn_update_dpp(
      0, __float_as_int(v), 0x143, 0xF, 0xF, true));  // row_bcast:31
  return v;
}

// Force a block-uniform value into an SGPR (frees VGPR pressure).
__device__ __forceinline__ float bcast_first(float v) {
  return __uint_as_float(__builtin_amdgcn_readfirstlane(__float_as_uint(v)));
}

// Pin a value into a VGPR as an opaque (non-rematerializable) register.
// R7 DIAGNOSIS: VGPR_Count=60 with budget 128 and clean WRITE_SIZE means the
// compiler was NOT keeping w0/w1[27] live -- it re-loaded all 54 weights from
// global (L2) EVERY inner iteration (remat), ~1.8GB/dispatch of hidden L2
// traffic. The empty asm makes each weight an opaque value the compiler
// cannot fold back into a load, forcing true register residency.
__device__ __forceinline__ void pin(float& v) {
  asm volatile("" : "+v"(v));
}

// One workgroup (256 threads = 4 waves) per 8^3 spatial block. Thread t owns a
// (1,1,2) micro-tile: p = t>>5, q = (t>>2)&7, r0 = 2*(t&3); 2x27 conv weights
// pinned in registers (batch-invariant). All 4 batches in flight.
// Ping-pong window buffers -> ONE barrier per inner iteration (8 phases).
// LDS window TRANSPOSED: addr = wp*120 + wk*12 + wq -> conv b32 reads hit
// every bank exactly 2x per wave (free; R4 cut conflicts 63x).
// 38.9KB LDS -> 4 WGs/CU -> compiler occupancy target 4 waves/EU -> 128-reg
// budget, enough for the ~95 this kernel needs once weights are pinned.
__global__ __launch_bounds__(256, 4) void gridnet_kernel(
    const float* __restrict__ weight, const float* __restrict__ bias,
    const float* __restrict__ rscale, const float* __restrict__ x,
    float* __restrict__ out) {
  __shared__ float Wl[NB][2][BUFSZ];   // 38400 B
  __shared__ float red[128];           // [0,64): staging; [64,96)/[96,128): iter banks

  const int t = threadIdx.x;
  const int r0 = (t & 3) * 2, q = (t >> 2) & 7, p = t >> 5;
  const int wv = t >> 6;

  // XCD swizzle: adjacent-bk spatial blocks (sharing 64B weight/x lines) land
  // on the same XCD -> second read hits that XCD's L2. (FETCH 575->139MB.)
  const int d = blockIdx.x;
  const int sp = (d & 7) * 512 + (d >> 3);
  const int bm = sp >> 8, bn = (sp >> 4) & 15, bk = sp & 15;

  const int gm0 = bm * 8, gn0 = bn * 8, gk0 = bk * 8;
  const int g = ((gm0 + p) * NN + (gn0 + q)) * KK + (gk0 + r0);

  // per-thread weights: w0/w1 = the two k-cells, o = i*9 + j*3 + k
  float w0[27], w1[27];
  float S0 = 0.f, S1 = 0.f;
#pragma unroll
  for (int o = 0; o < 27; ++o) {
    float2 wv2 = *(const float2*)(weight + o * MNK + g);
    w0[o] = wv2.x; w1[o] = wv2.y;
    S0 += wv2.x;   S1 += wv2.y;
  }
  float2 bv = *(const float2*)(bias + g);
  float2 rv = *(const float2*)(rscale + g);
  // Pin everything loop-invariant into registers (see comment on pin()).
#pragma unroll
  for (int o = 0; o < 27; ++o) { pin(w0[o]); pin(w1[o]); }
  pin(S0); pin(S1);
  pin(bv.x); pin(bv.y); pin(rv.x); pin(rv.y);

  // transposed window coords: addr(wp,wk,wq) = wp*PLANE + wk*WSTRIDE + wq
  const int cb = p * PLANE + r0 * WSTRIDE + q;   // (i=0,jj=0,k=0) tap
  const int wb = cb + PLANE + WSTRIDE + 1;       // own cell dr=0; dr=1 at +WSTRIDE

  // ---- stage all 4 batch windows into buf0; halo mirrored into buf1 ----
  float sA[NB] = {0.f, 0.f, 0.f, 0.f}, sAq[NB] = {0.f, 0.f, 0.f, 0.f};
  float sH[NB] = {0.f, 0.f, 0.f, 0.f}, sHq[NB] = {0.f, 0.f, 0.f, 0.f};
  for (int idx = t; idx < 1000; idx += 256) {
    int wp_ = idx / 100;
    int rem = idx - wp_ * 100;
    int wq = rem / 10;
    int wk = rem - wq * 10;
    int gm = gm0 - 1 + wp_, gn = gn0 - 1 + wq, gk = gk0 - 1 + wk;
    const bool inb = (unsigned)gm < 128u && (unsigned)gn < 128u && (unsigned)gk < 128u;
    const bool halo = (wp_ == 0 || wp_ == 9 || wq == 0 || wq == 9 || wk == 0 || wk == 9);
    const int gx = (gm * NN + gn) * KK + gk;        // only used when inb
    const int li = wp_ * PLANE + wk * WSTRIDE + wq; // transposed store
#pragma unroll
    for (int b = 0; b < NB; ++b) {
      float v = 0.f;
      if (inb) v = x[b * MNK + gx];
      Wl[b][0][li] = v;
      sA[b] += v; sAq[b] += v * v;
      if (halo) { Wl[b][1][li] = v; sH[b] += v; sHq[b] += v * v; }
    }
  }
#pragma unroll
  for (int b = 0; b < NB; ++b) {
    sA[b] = wave_sum63(sA[b]);  sAq[b] = wave_sum63(sAq[b]);
    sH[b] = wave_sum63(sH[b]);  sHq[b] = wave_sum63(sHq[b]);
  }
  if ((t & 63) == 63) {
#pragma unroll
    for (int b = 0; b < NB; ++b) {
      float4 pk; pk.x = sA[b]; pk.y = sAq[b]; pk.z = sH[b]; pk.w = sHq[b];
      *(float4*)&red[(wv * NB + b) * 4] = pk;
    }
  }
  __syncthreads();

  float invv[NB], imv[NB], hS[NB], hQ[NB];  // block-uniform -> SGPRs
#pragma unroll
  for (int b = 0; b < NB; ++b) {
    float tS = 0.f, tQ = 0.f, hs = 0.f, hq = 0.f;
#pragma unroll
    for (int i = 0; i < 4; ++i) {
      float4 pk = *(const float4*)&red[(i * NB + b) * 4];  // broadcast read
      tS += pk.x; tQ += pk.y; hs += pk.z; hq += pk.w;
    }
    hS[b] = bcast_first(hs); hQ[b] = bcast_first(hq);
    float mu = tS * (1.0f / 1000.0f);
    float var = tQ * (1.0f / 1000.0f) - mu * mu;
    float inv = __builtin_amdgcn_rsqf(var + 1e-5f);
    invv[b] = bcast_first(inv); imv[b] = bcast_first(inv * mu);
  }
  float a[NB][2];
#pragma unroll
  for (int b = 0; b < NB; ++b) {
    a[b][0] = Wl[b][0][wb];
    a[b][1] = Wl[b][0][wb + WSTRIDE];
  }

#pragma unroll 2
  for (int it = 0; it < ITERS; ++it) {
    const int cur = it & 1;
    // ---- 3^3 locally-connected conv + silu, all 4 batches, from buf[cur] ----
    // (normalization folded: z = bias + inv*conv_raw - inv*mu*S)
#pragma unroll
    for (int b = 0; b < NB; ++b) {
      const float* __restrict__ cp = &Wl[b][cur][cb];
      float acc0 = 0.f, acc1 = 0.f;
#pragma unroll
      for (int i = 0; i < 3; ++i) {
#pragma unroll
        for (int jj = 0; jj < 3; ++jj) {
          const float* rp = cp + i * PLANE + jj;
          float u0 = rp[0];
          float u1 = rp[WSTRIDE];
          float u2 = rp[2 * WSTRIDE];
          float u3 = rp[3 * WSTRIDE];
          const int o = i * 9 + jj * 3;
          acc0 += w0[o] * u0 + w0[o + 1] * u1 + w0[o + 2] * u2;
          acc1 += w1[o] * u1 + w1[o + 1] * u2 + w1[o + 2] * u3;
        }
      }
      float z0 = bv.x + invv[b] * acc0 - imv[b] * S0;
      float z1 = bv.y + invv[b] * acc1 - imv[b] * S1;
      float sg0 = __builtin_amdgcn_rcpf(1.0f + __expf(-z0));
      float sg1 = __builtin_amdgcn_rcpf(1.0f + __expf(-z1));
      a[b][0] += rv.x * (z0 * sg0);
      a[b][1] += rv.y * (z1 * sg1);
    }
    if (it == ITERS - 1) break;
    // ---- write new interiors into buf[cur^1] (WAR-safe: buf[cur^1] readers
    // finished before the barrier at the end of the previous iteration) ----
    float ls[NB], lq[NB];
#pragma unroll
    for (int b = 0; b < NB; ++b) {
      Wl[b][cur ^ 1][wb] = a[b][0];
      Wl[b][cur ^ 1][wb + WSTRIDE] = a[b][1];
      ls[b] = wave_sum63(a[b][0] + a[b][1]);
      lq[b] = wave_sum63(a[b][0] * a[b][0] + a[b][1] * a[b][1]);
    }
    const int bank = 64 + cur * 32;  // alternate banks: single-barrier race-free
    if ((t & 63) == 63) {
#pragma unroll
      for (int b = 0; b < NB; ++b) {
        float2 pk; pk.x = ls[b]; pk.y = lq[b];
        *(float2*)&red[bank + (wv * NB + b) * 2] = pk;
      }
    }
    __syncthreads();  // ONE barrier: interiors visible + partials ready
#pragma unroll
    for (int b = 0; b < NB; ++b) {
      float tS = hS[b], tQ = hQ[b];
#pragma unroll
      for (int i = 0; i < 4; ++i) {
        float2 pk = *(const float2*)&red[bank + (i * NB + b) * 2];  // broadcast
        tS += pk.x; tQ += pk.y;
      }
      float mu = tS * (1.0f / 1000.0f);
      float var = tQ * (1.0f / 1000.0f) - mu * mu;
      float inv = __builtin_amdgcn_rsqf(var + 1e-5f);
      invv[b] = bcast_first(inv); imv[b] = bcast_first(inv * mu);
    }
  }
  // ---- final interiors from registers (r0 even -> float2-aligned) ----
#pragma unroll
  for (int b = 0; b < NB; ++b) {
    float2 ov; ov.x = a[b][0]; ov.y = a[b][1];
    *(float2*)(out + b * MNK + g) = ov;
  }
}

extern "C" void kernel_launch(void* const* d_in, const int* in_sizes, int n_in,
                              void* d_out, int out_size, void* d_ws, size_t ws_size,
                              hipStream_t stream) {
  const float* weight = (const float*)d_in[0];
  const float* bias   = (const float*)d_in[1];
  const float* rscale = (const float*)d_in[2];
  const float* x      = (const float*)d_in[3];
  // d_in[4] = inner_iterations (8), d_in[5] = block_size (8): fixed by harness
  float* out = (float*)d_out;
  gridnet_kernel<<<dim3(16 * 16 * 16), dim3(256), 0, stream>>>(
      weight, bias, rscale, x, out);
}

// Round 9
// 168.303 us; speedup vs baseline: 1.2469x; 1.0439x over previous
//
#include <hip/hip_runtime.h>

#define MM 128
#define NN 128
#define KK 128
#define NB 4
#define ITERS 8
#define WIN 10
#define WSTRIDE 12
#define PLANE (WIN * WSTRIDE)   // wp stride: 10 wk-rows of 12
#define BUFSZ (WIN * PLANE)     // 1200 floats per window buffer
#define MNK (MM * NN * KK)

typedef float v2f __attribute__((ext_vector_type(2)));

// Wave-64 sum via DPP adds (no DS-pipe traffic, short dep chain).
// Result valid in LANE 63 only.
__device__ __forceinline__ float wave_sum63(float v) {
  v += __int_as_float(__builtin_amdgcn_update_dpp(
      0, __float_as_int(v), 0x111, 0xF, 0xF, true));  // row_shr:1
  v += __int_as_float(__builtin_amdgcn_update_dpp(
      0, __float_as_int(v), 0x112, 0xF, 0xF, true));  // row_shr:2
  v += __int_as_float(__builtin_amdgcn_update_dpp(
      0, __float_as_int(v), 0x114, 0xF, 0xF, true));  // row_shr:4
  v += __int_as_float(__builtin_amdgcn_update_dpp(
      0, __float_as_int(v), 0x118, 0xF, 0xF, true));  // row_shr:8
  v += __int_as_float(__builtin_amdgcn_update_dpp(
      0, __float_as_int(v), 0x142, 0xF, 0xF, true));  // row_bcast:15
  v += __int_as_float(__builtin_amdgcn_update_dpp(
      0, __float_as_int(v), 0x143, 0xF, 0xF, true));  // row_bcast:31
  return v;
}

// Force a block-uniform value into an SGPR (frees VGPR pressure).
__device__ __forceinline__ float bcast_first(float v) {
  return __uint_as_float(__builtin_amdgcn_readfirstlane(__float_as_uint(v)));
}

// Pin values as opaque registers (non-rematerializable; R8 win: stops the
// compiler from re-loading weights from global every iteration).
__device__ __forceinline__ void pin(float& v) { asm("" : "+v"(v)); }
__device__ __forceinline__ void pin2(v2f& v) { asm("" : "+v"(v)); }

// Packed dual-FP32 FMA (gfx90a+): d = a*b + d elementwise on 2 lanes.
// Scalar v_fma runs at HALF the 157TF fp32 peak; pk_fma is the full rate.
__device__ __forceinline__ void pk_fma(v2f& d, v2f a, v2f b) {
  asm("v_pk_fma_f32 %0, %1, %2, %0" : "+v"(d) : "v"(a), "v"(b));
}

// One workgroup (256 threads = 4 waves) per 8^3 spatial block. Thread t owns a
// (1,1,2) micro-tile: p = t>>5, q = (t>>2)&7, r0 = 2*(t&3); 27 float2 conv
// weight PAIRS {w_cell0[o], w_cell1[o]} pinned in registers (batch-invariant).
// All 4 batches in flight; ping-pong buffers -> ONE barrier per iteration.
// Conv inner uses v_pk_fma_f32: per tap-row the 6 products become
//   pk({wa0,wa1} x {u0,u1}) + pk({wc0,wc1} x {u2,u3}) + 2 scalar FMA
// (the middle {u1,u2} pair straddles the even-alignment boundary - unpairable).
// u pairs load as float2 halves -> compiler merges to ds_read2_b32.
// LDS window TRANSPOSED: addr = wp*120 + wk*12 + wq -> conv reads hit every
// bank exactly 2x per wave (free). 38.9KB LDS -> 4 WGs/CU -> 128-reg budget.
__global__ __launch_bounds__(256, 4) void gridnet_kernel(
    const float* __restrict__ weight, const float* __restrict__ bias,
    const float* __restrict__ rscale, const float* __restrict__ x,
    float* __restrict__ out) {
  __shared__ float Wl[NB][2][BUFSZ];   // 38400 B
  __shared__ float red[128];           // [0,64): staging; [64,96)/[96,128): iter banks

  const int t = threadIdx.x;
  const int r0 = (t & 3) * 2, q = (t >> 2) & 7, p = t >> 5;
  const int wv = t >> 6;

  // XCD swizzle: adjacent-bk spatial blocks (sharing 64B weight/x lines) land
  // on the same XCD -> second read hits that XCD's L2. (FETCH 575->139MB.)
  const int d = blockIdx.x;
  const int sp = (d & 7) * 512 + (d >> 3);
  const int bm = sp >> 8, bn = (sp >> 4) & 15, bk = sp & 15;

  const int gm0 = bm * 8, gn0 = bn * 8, gk0 = bk * 8;
  const int g = ((gm0 + p) * NN + (gn0 + q)) * KK + (gk0 + r0);

  // per-thread weights, packed by tap-row: row = i*3 + jj (9 rows), with
  // Pa[row] = pair at k-tap 0, Pm[row] = k-tap 1, Pc[row] = k-tap 2.
  v2f Pa[9], Pm[9], Pc[9];
  float S0 = 0.f, S1 = 0.f;
#pragma unroll
  for (int row = 0; row < 9; ++row) {
    const int o = row * 3;
    v2f wa = *(const v2f*)(weight + (o + 0) * MNK + g);
    v2f wm = *(const v2f*)(weight + (o + 1) * MNK + g);
    v2f wc = *(const v2f*)(weight + (o + 2) * MNK + g);
    Pa[row] = wa; Pm[row] = wm; Pc[row] = wc;
    S0 += wa.x + wm.x + wc.x;
    S1 += wa.y + wm.y + wc.y;
  }
  float2 bv = *(const float2*)(bias + g);
  float2 rv = *(const float2*)(rscale + g);
#pragma unroll
  for (int row = 0; row < 9; ++row) { pin2(Pa[row]); pin2(Pm[row]); pin2(Pc[row]); }
  pin(S0); pin(S1);
  pin(bv.x); pin(bv.y); pin(rv.x); pin(rv.y);

  // transposed window coords: addr(wp,wk,wq) = wp*PLANE + wk*WSTRIDE + wq
  const int cb = p * PLANE + r0 * WSTRIDE + q;   // (i=0,jj=0,k=0) tap
  const int wb = cb + PLANE + WSTRIDE + 1;       // own cell dr=0; dr=1 at +WSTRIDE

  // ---- stage all 4 batch windows into buf0; halo mirrored into buf1 ----
  float sA[NB] = {0.f, 0.f, 0.f, 0.f}, sAq[NB] = {0.f, 0.f, 0.f, 0.f};
  float sH[NB] = {0.f, 0.f, 0.f, 0.f}, sHq[NB] = {0.f, 0.f, 0.f, 0.f};
  for (int idx = t; idx < 1000; idx += 256) {
    int wp_ = idx / 100;
    int rem = idx - wp_ * 100;
    int wq = rem / 10;
    int wk = rem - wq * 10;
    int gm = gm0 - 1 + wp_, gn = gn0 - 1 + wq, gk = gk0 - 1 + wk;
    const bool inb = (unsigned)gm < 128u && (unsigned)gn < 128u && (unsigned)gk < 128u;
    const bool halo = (wp_ == 0 || wp_ == 9 || wq == 0 || wq == 9 || wk == 0 || wk == 9);
    const int gx = (gm * NN + gn) * KK + gk;        // only used when inb
    const int li = wp_ * PLANE + wk * WSTRIDE + wq; // transposed store
#pragma unroll
    for (int b = 0; b < NB; ++b) {
      float v = 0.f;
      if (inb) v = x[b * MNK + gx];
      Wl[b][0][li] = v;
      sA[b] += v; sAq[b] += v * v;
      if (halo) { Wl[b][1][li] = v; sH[b] += v; sHq[b] += v * v; }
    }
  }
#pragma unroll
  for (int b = 0; b < NB; ++b) {
    sA[b] = wave_sum63(sA[b]);  sAq[b] = wave_sum63(sAq[b]);
    sH[b] = wave_sum63(sH[b]);  sHq[b] = wave_sum63(sHq[b]);
  }
  if ((t & 63) == 63) {
#pragma unroll
    for (int b = 0; b < NB; ++b) {
      float4 pk; pk.x = sA[b]; pk.y = sAq[b]; pk.z = sH[b]; pk.w = sHq[b];
      *(float4*)&red[(wv * NB + b) * 4] = pk;
    }
  }
  __syncthreads();

  float invv[NB], imv[NB], hS[NB], hQ[NB];  // block-uniform -> SGPRs
#pragma unroll
  for (int b = 0; b < NB; ++b) {
    float tS = 0.f, tQ = 0.f, hs = 0.f, hq = 0.f;
#pragma unroll
    for (int i = 0; i < 4; ++i) {
      float4 pk = *(const float4*)&red[(i * NB + b) * 4];  // broadcast read
      tS += pk.x; tQ += pk.y; hs += pk.z; hq += pk.w;
    }
    hS[b] = bcast_first(hs); hQ[b] = bcast_first(hq);
    float mu = tS * (1.0f / 1000.0f);
    float var = tQ * (1.0f / 1000.0f) - mu * mu;
    float inv = __builtin_amdgcn_rsqf(var + 1e-5f);
    invv[b] = bcast_first(inv); imv[b] = bcast_first(inv * mu);
  }
  float a[NB][2];
#pragma unroll
  for (int b = 0; b < NB; ++b) {
    a[b][0] = Wl[b][0][wb];
    a[b][1] = Wl[b][0][wb + WSTRIDE];
  }

#pragma unroll 2
  for (int it = 0; it < ITERS; ++it) {
    const int cur = it & 1;
    // ---- 3^3 locally-connected conv + silu, all 4 batches, from buf[cur] ----
    // (normalization folded: z = bias + inv*conv_raw - inv*mu*S)
#pragma unroll
    for (int b = 0; b < NB; ++b) {
      const float* __restrict__ cp = &Wl[b][cur][cb];
      v2f accp = {0.f, 0.f};
#pragma unroll
      for (int i = 0; i < 3; ++i) {
#pragma unroll
        for (int jj = 0; jj < 3; ++jj) {
          const float* rp = cp + i * PLANE + jj;
          const int row = i * 3 + jj;
          v2f U01, U23;                 // halves merge into ds_read2_b32
          U01.x = rp[0];
          U01.y = rp[WSTRIDE];
          U23.x = rp[2 * WSTRIDE];
          U23.y = rp[3 * WSTRIDE];
          pk_fma(accp, Pa[row], U01);   // acc0 += wa0*u0 ; acc1 += wa1*u1
          pk_fma(accp, Pc[row], U23);   // acc0 += wc0*u2 ; acc1 += wc1*u3
          accp.x += Pm[row].x * U01.y;  // acc0 += wm0*u1
          accp.y += Pm[row].y * U23.x;  // acc1 += wm1*u2
        }
      }
      float z0 = bv.x + invv[b] * accp.x - imv[b] * S0;
      float z1 = bv.y + invv[b] * accp.y - imv[b] * S1;
      float sg0 = __builtin_amdgcn_rcpf(1.0f + __expf(-z0));
      float sg1 = __builtin_amdgcn_rcpf(1.0f + __expf(-z1));
      a[b][0] += rv.x * (z0 * sg0);
      a[b][1] += rv.y * (z1 * sg1);
    }
    if (it == ITERS - 1) break;
    // ---- write new interiors into buf[cur^1] (WAR-safe: buf[cur^1] readers
    // finished before the barrier at the end of the previous iteration) ----
    float ls[NB], lq[NB];
#pragma unroll
    for (int b = 0; b < NB; ++b) {
      Wl[b][cur ^ 1][wb] = a[b][0];
      Wl[b][cur ^ 1][wb + WSTRIDE] = a[b][1];
      ls[b] = wave_sum63(a[b][0] + a[b][1]);
      lq[b] = wave_sum63(a[b][0] * a[b][0] + a[b][1] * a[b][1]);
    }
    const int bank = 64 + cur * 32;  // alternate banks: single-barrier race-free
    if ((t & 63) == 63) {
#pragma unroll
      for (int b = 0; b < NB; ++b) {
        float2 pk; pk.x = ls[b]; pk.y = lq[b];
        *(float2*)&red[bank + (wv * NB + b) * 2] = pk;
      }
    }
    __syncthreads();  // ONE barrier: interiors visible + partials ready
#pragma unroll
    for (int b = 0; b < NB; ++b) {
      float tS = hS[b], tQ = hQ[b];
#pragma unroll
      for (int i = 0; i < 4; ++i) {
        float2 pk = *(const float2*)&red[bank + (i * NB + b) * 2];  // broadcast
        tS += pk.x; tQ += pk.y;
      }
      float mu = tS * (1.0f / 1000.0f);
      float var = tQ * (1.0f / 1000.0f) - mu * mu;
      float inv = __builtin_amdgcn_rsqf(var + 1e-5f);
      invv[b] = bcast_first(inv); imv[b] = bcast_first(inv * mu);
    }
  }
  // ---- final interiors from registers (r0 even -> float2-aligned) ----
#pragma unroll
  for (int b = 0; b < NB; ++b) {
    float2 ov; ov.x = a[b][0]; ov.y = a[b][1];
    *(float2*)(out + b * MNK + g) = ov;
  }
}

extern "C" void kernel_launch(void* const* d_in, const int* in_sizes, int n_in,
                              void* d_out, int out_size, void* d_ws, size_t ws_size,
                              hipStream_t stream) {
  const float* weight = (const float*)d_in[0];
  const float* bias   = (const float*)d_in[1];
  const float* rscale = (const float*)d_in[2];
  const float* x      = (const float*)d_in[3];
  // d_in[4] = inner_iterations (8), d_in[5] = block_size (8): fixed by harness
  float* out = (float*)d_out;
  gridnet_kernel<<<dim3(16 * 16 * 16), dim3(256), 0, stream>>>(
      weight, bias, rscale, x, out);
}

// Round 10
// 167.597 us; speedup vs baseline: 1.2522x; 1.0042x over previous
//
#include <hip/hip_runtime.h>

#define MM 128
#define NN 128
#define KK 128
#define NB 4
#define ITERS 8
#define WIN 10
#define WSTRIDE 12
#define PLANE (WIN * WSTRIDE)   // wp stride: 10 wk-rows of 12
#define BUFSZ (WIN * PLANE)     // 1200 floats per window buffer
#define MNK (MM * NN * KK)

typedef float v2f __attribute__((ext_vector_type(2)));

// Wave-64 sum via DPP adds (no DS-pipe traffic, short dep chain).
// Result valid in LANE 63 only.
__device__ __forceinline__ float wave_sum63(float v) {
  v += __int_as_float(__builtin_amdgcn_update_dpp(
      0, __float_as_int(v), 0x111, 0xF, 0xF, true));  // row_shr:1
  v += __int_as_float(__builtin_amdgcn_update_dpp(
      0, __float_as_int(v), 0x112, 0xF, 0xF, true));  // row_shr:2
  v += __int_as_float(__builtin_amdgcn_update_dpp(
      0, __float_as_int(v), 0x114, 0xF, 0xF, true));  // row_shr:4
  v += __int_as_float(__builtin_amdgcn_update_dpp(
      0, __float_as_int(v), 0x118, 0xF, 0xF, true));  // row_shr:8
  v += __int_as_float(__builtin_amdgcn_update_dpp(
      0, __float_as_int(v), 0x142, 0xF, 0xF, true));  // row_bcast:15
  v += __int_as_float(__builtin_amdgcn_update_dpp(
      0, __float_as_int(v), 0x143, 0xF, 0xF, true));  // row_bcast:31
  return v;
}

// Force a block-uniform value into an SGPR (frees VGPR pressure).
__device__ __forceinline__ float bcast_first(float v) {
  return __uint_as_float(__builtin_amdgcn_readfirstlane(__float_as_uint(v)));
}

// Pin values as opaque registers (non-rematerializable; R8 win: stops the
// compiler from re-loading weights from global every iteration).
__device__ __forceinline__ void pin(float& v) { asm("" : "+v"(v)); }
__device__ __forceinline__ void pin2(v2f& v) { asm("" : "+v"(v)); }

// Packed dual-FP32 FMA (gfx90a+): d = a*b + d elementwise on 2 lanes.
__device__ __forceinline__ void pk_fma(v2f& d, v2f a, v2f b) {
  asm("v_pk_fma_f32 %0, %1, %2, %0" : "+v"(d) : "v"(a), "v"(b));
}

// One workgroup (256 threads = 4 waves) per 8^3 spatial block. Thread t owns a
// (1,1,2) micro-tile; 27 float2 weight pairs pinned in registers; 4 batches in
// flight; ping-pong buffers -> ONE barrier/iteration; transposed LDS window
// (conflict-free); XCD swizzle.
//
// R10 CHANGE (read-latency pipeline): occupancy is register-bound at ~3.3
// waves/SIMD (512-reg unified file / ~154 combined VGPR+AGPR). With only 56
// arch VGPRs, the scheduler could keep only ~5 ds_read2 in flight -> a
// ~120-cyc lgkmcnt stall every few reads, unhidden at 3.3 waves. Fix: each
// batch's conv now ISSUES ALL 18 ds_read2 into a U[9]x2 register block
// (36 dwords), THEN runs all 36 FMAs. The 18-deep read burst (~108 cyc of
// issue) covers the LDS latency within a single wave; costs ~30 VGPRs
// (occupancy ~2.9/SIMD), which the stall reduction should more than repay.
__global__ __launch_bounds__(256, 4) void gridnet_kernel(
    const float* __restrict__ weight, const float* __restrict__ bias,
    const float* __restrict__ rscale, const float* __restrict__ x,
    float* __restrict__ out) {
  __shared__ float Wl[NB][2][BUFSZ];   // 38400 B
  __shared__ float red[128];           // [0,64): staging; [64,96)/[96,128): iter banks

  const int t = threadIdx.x;
  const int r0 = (t & 3) * 2, q = (t >> 2) & 7, p = t >> 5;
  const int wv = t >> 6;

  // XCD swizzle: adjacent-bk spatial blocks (sharing 64B weight/x lines) land
  // on the same XCD -> second read hits that XCD's L2. (FETCH 575->139MB.)
  const int d = blockIdx.x;
  const int sp = (d & 7) * 512 + (d >> 3);
  const int bm = sp >> 8, bn = (sp >> 4) & 15, bk = sp & 15;

  const int gm0 = bm * 8, gn0 = bn * 8, gk0 = bk * 8;
  const int g = ((gm0 + p) * NN + (gn0 + q)) * KK + (gk0 + r0);

  // per-thread weights, packed by tap-row: row = i*3 + jj (9 rows), with
  // Pa[row] = pair at k-tap 0, Pm[row] = k-tap 1, Pc[row] = k-tap 2.
  v2f Pa[9], Pm[9], Pc[9];
  float S0 = 0.f, S1 = 0.f;
#pragma unroll
  for (int row = 0; row < 9; ++row) {
    const int o = row * 3;
    v2f wa = *(const v2f*)(weight + (o + 0) * MNK + g);
    v2f wm = *(const v2f*)(weight + (o + 1) * MNK + g);
    v2f wc = *(const v2f*)(weight + (o + 2) * MNK + g);
    Pa[row] = wa; Pm[row] = wm; Pc[row] = wc;
    S0 += wa.x + wm.x + wc.x;
    S1 += wa.y + wm.y + wc.y;
  }
  float2 bv = *(const float2*)(bias + g);
  float2 rv = *(const float2*)(rscale + g);
#pragma unroll
  for (int row = 0; row < 9; ++row) { pin2(Pa[row]); pin2(Pm[row]); pin2(Pc[row]); }
  pin(S0); pin(S1);
  pin(bv.x); pin(bv.y); pin(rv.x); pin(rv.y);

  // transposed window coords: addr(wp,wk,wq) = wp*PLANE + wk*WSTRIDE + wq
  const int cb = p * PLANE + r0 * WSTRIDE + q;   // (i=0,jj=0,k=0) tap
  const int wb = cb + PLANE + WSTRIDE + 1;       // own cell dr=0; dr=1 at +WSTRIDE

  // ---- stage all 4 batch windows into buf0; halo mirrored into buf1 ----
  float sA[NB] = {0.f, 0.f, 0.f, 0.f}, sAq[NB] = {0.f, 0.f, 0.f, 0.f};
  float sH[NB] = {0.f, 0.f, 0.f, 0.f}, sHq[NB] = {0.f, 0.f, 0.f, 0.f};
  for (int idx = t; idx < 1000; idx += 256) {
    int wp_ = idx / 100;
    int rem = idx - wp_ * 100;
    int wq = rem / 10;
    int wk = rem - wq * 10;
    int gm = gm0 - 1 + wp_, gn = gn0 - 1 + wq, gk = gk0 - 1 + wk;
    const bool inb = (unsigned)gm < 128u && (unsigned)gn < 128u && (unsigned)gk < 128u;
    const bool halo = (wp_ == 0 || wp_ == 9 || wq == 0 || wq == 9 || wk == 0 || wk == 9);
    const int gx = (gm * NN + gn) * KK + gk;        // only used when inb
    const int li = wp_ * PLANE + wk * WSTRIDE + wq; // transposed store
#pragma unroll
    for (int b = 0; b < NB; ++b) {
      float v = 0.f;
      if (inb) v = x[b * MNK + gx];
      Wl[b][0][li] = v;
      sA[b] += v; sAq[b] += v * v;
      if (halo) { Wl[b][1][li] = v; sH[b] += v; sHq[b] += v * v; }
    }
  }
#pragma unroll
  for (int b = 0; b < NB; ++b) {
    sA[b] = wave_sum63(sA[b]);  sAq[b] = wave_sum63(sAq[b]);
    sH[b] = wave_sum63(sH[b]);  sHq[b] = wave_sum63(sHq[b]);
  }
  if ((t & 63) == 63) {
#pragma unroll
    for (int b = 0; b < NB; ++b) {
      float4 pk; pk.x = sA[b]; pk.y = sAq[b]; pk.z = sH[b]; pk.w = sHq[b];
      *(float4*)&red[(wv * NB + b) * 4] = pk;
    }
  }
  __syncthreads();

  float invv[NB], imv[NB], hS[NB], hQ[NB];  // block-uniform -> SGPRs
#pragma unroll
  for (int b = 0; b < NB; ++b) {
    float tS = 0.f, tQ = 0.f, hs = 0.f, hq = 0.f;
#pragma unroll
    for (int i = 0; i < 4; ++i) {
      float4 pk = *(const float4*)&red[(i * NB + b) * 4];  // broadcast read
      tS += pk.x; tQ += pk.y; hs += pk.z; hq += pk.w;
    }
    hS[b] = bcast_first(hs); hQ[b] = bcast_first(hq);
    float mu = tS * (1.0f / 1000.0f);
    float var = tQ * (1.0f / 1000.0f) - mu * mu;
    float inv = __builtin_amdgcn_rsqf(var + 1e-5f);
    invv[b] = bcast_first(inv); imv[b] = bcast_first(inv * mu);
  }
  float a[NB][2];
#pragma unroll
  for (int b = 0; b < NB; ++b) {
    a[b][0] = Wl[b][0][wb];
    a[b][1] = Wl[b][0][wb + WSTRIDE];
  }

#pragma unroll 2
  for (int it = 0; it < ITERS; ++it) {
    const int cur = it & 1;
    // ---- 3^3 locally-connected conv + silu, all 4 batches, from buf[cur] ----
    // (normalization folded: z = bias + inv*conv_raw - inv*mu*S)
#pragma unroll
    for (int b = 0; b < NB; ++b) {
      const float* __restrict__ cp = &Wl[b][cur][cb];
      // Phase 1: issue ALL 18 ds_read2 into registers (latency pipeline).
      v2f U01[9], U23[9];
#pragma unroll
      for (int i = 0; i < 3; ++i)
#pragma unroll
        for (int jj = 0; jj < 3; ++jj) {
          const int row = i * 3 + jj;
          const float* rp = cp + i * PLANE + jj;
          v2f u01, u23;
          u01.x = rp[0];
          u01.y = rp[WSTRIDE];
          u23.x = rp[2 * WSTRIDE];
          u23.y = rp[3 * WSTRIDE];
          U01[row] = u01;
          U23[row] = u23;
        }
      // Phase 2: consume (2 pk_fma + 2 scalar fma per tap-row).
      v2f accp = {0.f, 0.f};
#pragma unroll
      for (int row = 0; row < 9; ++row) {
        pk_fma(accp, Pa[row], U01[row]);   // acc0 += wa0*u0 ; acc1 += wa1*u1
        pk_fma(accp, Pc[row], U23[row]);   // acc0 += wc0*u2 ; acc1 += wc1*u3
        accp.x += Pm[row].x * U01[row].y;  // acc0 += wm0*u1
        accp.y += Pm[row].y * U23[row].x;  // acc1 += wm1*u2
      }
      float z0 = bv.x + invv[b] * accp.x - imv[b] * S0;
      float z1 = bv.y + invv[b] * accp.y - imv[b] * S1;
      float sg0 = __builtin_amdgcn_rcpf(1.0f + __expf(-z0));
      float sg1 = __builtin_amdgcn_rcpf(1.0f + __expf(-z1));
      a[b][0] += rv.x * (z0 * sg0);
      a[b][1] += rv.y * (z1 * sg1);
    }
    if (it == ITERS - 1) break;
    // ---- write new interiors into buf[cur^1] (WAR-safe: buf[cur^1] readers
    // finished before the barrier at the end of the previous iteration) ----
    float ls[NB], lq[NB];
#pragma unroll
    for (int b = 0; b < NB; ++b) {
      Wl[b][cur ^ 1][wb] = a[b][0];
      Wl[b][cur ^ 1][wb + WSTRIDE] = a[b][1];
      ls[b] = wave_sum63(a[b][0] + a[b][1]);
      lq[b] = wave_sum63(a[b][0] * a[b][0] + a[b][1] * a[b][1]);
    }
    const int bank = 64 + cur * 32;  // alternate banks: single-barrier race-free
    if ((t & 63) == 63) {
#pragma unroll
      for (int b = 0; b < NB; ++b) {
        float2 pk; pk.x = ls[b]; pk.y = lq[b];
        *(float2*)&red[bank + (wv * NB + b) * 2] = pk;
      }
    }
    __syncthreads();  // ONE barrier: interiors visible + partials ready
#pragma unroll
    for (int b = 0; b < NB; ++b) {
      float tS = hS[b], tQ = hQ[b];
#pragma unroll
      for (int i = 0; i < 4; ++i) {
        float2 pk = *(const float2*)&red[bank + (i * NB + b) * 2];  // broadcast
        tS += pk.x; tQ += pk.y;
      }
      float mu = tS * (1.0f / 1000.0f);
      float var = tQ * (1.0f / 1000.0f) - mu * mu;
      float inv = __builtin_amdgcn_rsqf(var + 1e-5f);
      invv[b] = bcast_first(inv); imv[b] = bcast_first(inv * mu);
    }
  }
  // ---- final interiors from registers (r0 even -> float2-aligned) ----
#pragma unroll
  for (int b = 0; b < NB; ++b) {
    float2 ov; ov.x = a[b][0]; ov.y = a[b][1];
    *(float2*)(out + b * MNK + g) = ov;
  }
}

extern "C" void kernel_launch(void* const* d_in, const int* in_sizes, int n_in,
                              void* d_out, int out_size, void* d_ws, size_t ws_size,
                              hipStream_t stream) {
  const float* weight = (const float*)d_in[0];
  const float* bias   = (const float*)d_in[1];
  const float* rscale = (const float*)d_in[2];
  const float* x      = (const float*)d_in[3];
  // d_in[4] = inner_iterations (8), d_in[5] = block_size (8): fixed by harness
  float* out = (float*)d_out;
  gridnet_kernel<<<dim3(16 * 16 * 16), dim3(256), 0, stream>>>(
      weight, bias, rscale, x, out);
}

// Round 11
// 164.603 us; speedup vs baseline: 1.2750x; 1.0182x over previous
//
#include <hip/hip_runtime.h>

#define MM 128
#define NN 128
#define KK 128
#define NB 4
#define ITERS 8
#define WIN 10
#define PRS 24                  // k-pair stride (dwords): 12 q-slots x 2
#define QS 2                    // q stride (dwords) in pair-interleaved layout
#define PLANE 120               // 5 k-pairs x 24 dwords per wp-plane
#define BUFSZ (WIN * PLANE)     // 1200 floats per window buffer
#define MNK (MM * NN * KK)

typedef float v2f __attribute__((ext_vector_type(2)));

// Wave-64 sum via DPP adds (no DS-pipe traffic, short dep chain).
// Result valid in LANE 63 only.
__device__ __forceinline__ float wave_sum63(float v) {
  v += __int_as_float(__builtin_amdgcn_update_dpp(
      0, __float_as_int(v), 0x111, 0xF, 0xF, true));  // row_shr:1
  v += __int_as_float(__builtin_amdgcn_update_dpp(
      0, __float_as_int(v), 0x112, 0xF, 0xF, true));  // row_shr:2
  v += __int_as_float(__builtin_amdgcn_update_dpp(
      0, __float_as_int(v), 0x114, 0xF, 0xF, true));  // row_shr:4
  v += __int_as_float(__builtin_amdgcn_update_dpp(
      0, __float_as_int(v), 0x118, 0xF, 0xF, true));  // row_shr:8
  v += __int_as_float(__builtin_amdgcn_update_dpp(
      0, __float_as_int(v), 0x142, 0xF, 0xF, true));  // row_bcast:15
  v += __int_as_float(__builtin_amdgcn_update_dpp(
      0, __float_as_int(v), 0x143, 0xF, 0xF, true));  // row_bcast:31
  return v;
}

// Force a block-uniform value into an SGPR (frees VGPR pressure).
__device__ __forceinline__ float bcast_first(float v) {
  return __uint_as_float(__builtin_amdgcn_readfirstlane(__float_as_uint(v)));
}

// Pin values as opaque registers (non-rematerializable; R8 win: stops the
// compiler from re-loading weights from global every iteration).
__device__ __forceinline__ void pin(float& v) { asm("" : "+v"(v)); }
__device__ __forceinline__ void pin2(v2f& v) { asm("" : "+v"(v)); }

// Packed dual-FP32 FMA (gfx90a+): d = a*b + d elementwise on 2 lanes.
__device__ __forceinline__ void pk_fma(v2f& d, v2f a, v2f b) {
  asm("v_pk_fma_f32 %0, %1, %2, %0" : "+v"(d) : "v"(a), "v"(b));
}

// One workgroup (256 threads = 4 waves) per 8^3 spatial block. Thread t owns a
// (1,1,2) micro-tile; 27 float2 weight pairs pinned in registers; 4 batches in
// flight; ping-pong buffers -> ONE barrier/iteration; XCD swizzle.
//
// R11 CHANGE (DS instruction halving): the DS pipe is per-CU and its
// INSTRUCTION cost dominated (72 ds_read2_b32/thread/iter ~ 100us/CU of the
// 168us wall; R10 showed latency-staging is null -> issue count is the bind).
// The window layout is PAIR-INTERLEAVED along k:
//   L(wp,wq,wk) = wp*120 + (wk>>1)*24 + wq*2 + (wk&1)
// so a tap-row's 4 k-taps are two contiguous 8B pairs 96B apart -> ONE
// ds_read2_b64 per tap-row: 9 reads/batch-conv instead of 18. Same bytes,
// same registers; result pairs {u0,u1},{u2,u3} feed pk_fma directly.
// Banks: first-dword bank = (24(p+r2)+2q)%32 -> every even bank gets exactly
// 4 of the 128 dword-accesses = the 1KB/wave floor -> conflict-free.
__global__ __launch_bounds__(256, 4) void gridnet_kernel(
    const float* __restrict__ weight, const float* __restrict__ bias,
    const float* __restrict__ rscale, const float* __restrict__ x,
    float* __restrict__ out) {
  __shared__ __align__(16) float Wl[NB][2][BUFSZ];   // 38400 B
  __shared__ float red[128];           // [0,64): staging; [64,96)/[96,128): iter banks

  const int t = threadIdx.x;
  const int r0 = (t & 3) * 2, q = (t >> 2) & 7, p = t >> 5;
  const int wv = t >> 6;

  // XCD swizzle: adjacent-bk spatial blocks (sharing 64B weight/x lines) land
  // on the same XCD -> second read hits that XCD's L2. (FETCH 575->139MB.)
  const int d = blockIdx.x;
  const int sp = (d & 7) * 512 + (d >> 3);
  const int bm = sp >> 8, bn = (sp >> 4) & 15, bk = sp & 15;

  const int gm0 = bm * 8, gn0 = bn * 8, gk0 = bk * 8;
  const int g = ((gm0 + p) * NN + (gn0 + q)) * KK + (gk0 + r0);

  // per-thread weights, packed by tap-row: row = i*3 + jj (9 rows), with
  // Pa[row] = pair at k-tap 0, Pm[row] = k-tap 1, Pc[row] = k-tap 2.
  v2f Pa[9], Pm[9], Pc[9];
  float S0 = 0.f, S1 = 0.f;
#pragma unroll
  for (int row = 0; row < 9; ++row) {
    const int o = row * 3;
    v2f wa = *(const v2f*)(weight + (o + 0) * MNK + g);
    v2f wm = *(const v2f*)(weight + (o + 1) * MNK + g);
    v2f wc = *(const v2f*)(weight + (o + 2) * MNK + g);
    Pa[row] = wa; Pm[row] = wm; Pc[row] = wc;
    S0 += wa.x + wm.x + wc.x;
    S1 += wa.y + wm.y + wc.y;
  }
  float2 bv = *(const float2*)(bias + g);
  float2 rv = *(const float2*)(rscale + g);
#pragma unroll
  for (int row = 0; row < 9; ++row) { pin2(Pa[row]); pin2(Pm[row]); pin2(Pc[row]); }
  pin(S0); pin(S1);
  pin(bv.x); pin(bv.y); pin(rv.x); pin(rv.y);

  // pair-interleaved window coords (see header comment)
  const int cb = p * PLANE + (r0 >> 1) * PRS + q * QS;      // (i=0,jj=0) tap base
  const int wb1 = (p + 1) * PLANE + (r0 >> 1) * PRS + (q + 1) * QS + 1;  // cell dr=0
  const int wb2 = wb1 + PRS - 1;                                          // cell dr=1

  // ---- stage all 4 batch windows into buf0; halo mirrored into buf1 ----
  float sA[NB] = {0.f, 0.f, 0.f, 0.f}, sAq[NB] = {0.f, 0.f, 0.f, 0.f};
  float sH[NB] = {0.f, 0.f, 0.f, 0.f}, sHq[NB] = {0.f, 0.f, 0.f, 0.f};
  for (int idx = t; idx < 1000; idx += 256) {
    int wp_ = idx / 100;
    int rem = idx - wp_ * 100;
    int wq = rem / 10;
    int wk = rem - wq * 10;
    int gm = gm0 - 1 + wp_, gn = gn0 - 1 + wq, gk = gk0 - 1 + wk;
    const bool inb = (unsigned)gm < 128u && (unsigned)gn < 128u && (unsigned)gk < 128u;
    const bool halo = (wp_ == 0 || wp_ == 9 || wq == 0 || wq == 9 || wk == 0 || wk == 9);
    const int gx = (gm * NN + gn) * KK + gk;        // only used when inb
    const int li = wp_ * PLANE + (wk >> 1) * PRS + wq * QS + (wk & 1);
#pragma unroll
    for (int b = 0; b < NB; ++b) {
      float v = 0.f;
      if (inb) v = x[b * MNK + gx];
      Wl[b][0][li] = v;
      sA[b] += v; sAq[b] += v * v;
      if (halo) { Wl[b][1][li] = v; sH[b] += v; sHq[b] += v * v; }
    }
  }
#pragma unroll
  for (int b = 0; b < NB; ++b) {
    sA[b] = wave_sum63(sA[b]);  sAq[b] = wave_sum63(sAq[b]);
    sH[b] = wave_sum63(sH[b]);  sHq[b] = wave_sum63(sHq[b]);
  }
  if ((t & 63) == 63) {
#pragma unroll
    for (int b = 0; b < NB; ++b) {
      float4 pk; pk.x = sA[b]; pk.y = sAq[b]; pk.z = sH[b]; pk.w = sHq[b];
      *(float4*)&red[(wv * NB + b) * 4] = pk;
    }
  }
  __syncthreads();

  float invv[NB], imv[NB], hS[NB], hQ[NB];  // block-uniform -> SGPRs
#pragma unroll
  for (int b = 0; b < NB; ++b) {
    float tS = 0.f, tQ = 0.f, hs = 0.f, hq = 0.f;
#pragma unroll
    for (int i = 0; i < 4; ++i) {
      float4 pk = *(const float4*)&red[(i * NB + b) * 4];  // broadcast read
      tS += pk.x; tQ += pk.y; hs += pk.z; hq += pk.w;
    }
    hS[b] = bcast_first(hs); hQ[b] = bcast_first(hq);
    float mu = tS * (1.0f / 1000.0f);
    float var = tQ * (1.0f / 1000.0f) - mu * mu;
    float inv = __builtin_amdgcn_rsqf(var + 1e-5f);
    invv[b] = bcast_first(inv); imv[b] = bcast_first(inv * mu);
  }
  float a[NB][2];
#pragma unroll
  for (int b = 0; b < NB; ++b) {
    a[b][0] = Wl[b][0][wb1];
    a[b][1] = Wl[b][0][wb2];
  }

#pragma unroll 2
  for (int it = 0; it < ITERS; ++it) {
    const int cur = it & 1;
    // ---- 3^3 locally-connected conv + silu, all 4 batches, from buf[cur] ----
    // (normalization folded: z = bias + inv*conv_raw - inv*mu*S)
#pragma unroll
    for (int b = 0; b < NB; ++b) {
      const float* __restrict__ cp = &Wl[b][cur][cb];
      v2f accp = {0.f, 0.f};
#pragma unroll
      for (int i = 0; i < 3; ++i)
#pragma unroll
        for (int jj = 0; jj < 3; ++jj) {
          const int row = i * 3 + jj;
          const float* rp = cp + i * PLANE + jj * QS;
          v2f U01 = *(const v2f*)rp;          // {u0,u1}: one half of ds_read2_b64
          v2f U23 = *(const v2f*)(rp + PRS);  // {u2,u3}: other half (off +96B)
          pk_fma(accp, Pa[row], U01);   // acc0 += wa0*u0 ; acc1 += wa1*u1
          pk_fma(accp, Pc[row], U23);   // acc0 += wc0*u2 ; acc1 += wc1*u3
          accp.x += Pm[row].x * U01.y;  // acc0 += wm0*u1
          accp.y += Pm[row].y * U23.x;  // acc1 += wm1*u2
        }
      float z0 = bv.x + invv[b] * accp.x - imv[b] * S0;
      float z1 = bv.y + invv[b] * accp.y - imv[b] * S1;
      float sg0 = __builtin_amdgcn_rcpf(1.0f + __expf(-z0));
      float sg1 = __builtin_amdgcn_rcpf(1.0f + __expf(-z1));
      a[b][0] += rv.x * (z0 * sg0);
      a[b][1] += rv.y * (z1 * sg1);
    }
    if (it == ITERS - 1) break;
    // ---- write new interiors into buf[cur^1] (WAR-safe: buf[cur^1] readers
    // finished before the barrier at the end of the previous iteration) ----
    float ls[NB], lq[NB];
#pragma unroll
    for (int b = 0; b < NB; ++b) {
      Wl[b][cur ^ 1][wb1] = a[b][0];
      Wl[b][cur ^ 1][wb2] = a[b][1];
      ls[b] = wave_sum63(a[b][0] + a[b][1]);
      lq[b] = wave_sum63(a[b][0] * a[b][0] + a[b][1] * a[b][1]);
    }
    const int bank = 64 + cur * 32;  // alternate banks: single-barrier race-free
    if ((t & 63) == 63) {
#pragma unroll
      for (int b = 0; b < NB; ++b) {
        float2 pk; pk.x = ls[b]; pk.y = lq[b];
        *(float2*)&red[bank + (wv * NB + b) * 2] = pk;
      }
    }
    __syncthreads();  // ONE barrier: interiors visible + partials ready
#pragma unroll
    for (int b = 0; b < NB; ++b) {
      float tS = hS[b], tQ = hQ[b];
#pragma unroll
      for (int i = 0; i < 4; ++i) {
        float2 pk = *(const float2*)&red[bank + (i * NB + b) * 2];  // broadcast
        tS += pk.x; tQ += pk.y;
      }
      float mu = tS * (1.0f / 1000.0f);
      float var = tQ * (1.0f / 1000.0f) - mu * mu;
      float inv = __builtin_amdgcn_rsqf(var + 1e-5f);
      invv[b] = bcast_first(inv); imv[b] = bcast_first(inv * mu);
    }
  }
  // ---- final interiors from registers (r0 even -> float2-aligned) ----
#pragma unroll
  for (int b = 0; b < NB; ++b) {
    float2 ov; ov.x = a[b][0]; ov.y = a[b][1];
    *(float2*)(out + b * MNK + g) = ov;
  }
}

extern "C" void kernel_launch(void* const* d_in, const int* in_sizes, int n_in,
                              void* d_out, int out_size, void* d_ws, size_t ws_size,
                              hipStream_t stream) {
  const float* weight = (const float*)d_in[0];
  const float* bias   = (const float*)d_in[1];
  const float* rscale = (const float*)d_in[2];
  const float* x      = (const float*)d_in[3];
  // d_in[4] = inner_iterations (8), d_in[5] = block_size (8): fixed by harness
  float* out = (float*)d_out;
  gridnet_kernel<<<dim3(16 * 16 * 16), dim3(256), 0, stream>>>(
      weight, bias, rscale, x, out);
}